// Round 1
// baseline (91.420 us; speedup 1.0000x reference)
//
#include <hip/hip_runtime.h>

// 1D periodic diffusion, 50 steps, emit all intermediate states.
// out[t,b,n,d], t=0..50. Write-BW-bound (428 MB out). Halo/trapezoid
// decomposition: each block owns T rows of n for one b, loads T+104 rows
// (>=50 halo each side, wraparound at load), runs all 50 steps in
// registers, stores each step's owned rows. No inter-block sync.

namespace {

constexpr int   B      = 8;
constexpr int   N      = 2048;
constexpr int   D4     = 32;    // 128 floats = 32 float4 per row
constexpr int   STEPS  = 50;
constexpr float ALPHA  = 0.1f;
constexpr int   T      = 32;    // owned rows per block
constexpr int   HALO_L = 50;
constexpr int   R      = 136;   // T + 104 >= T + 100, multiple of QG
constexpr int   QG     = 8;     // row-groups (q) per block
constexpr int   K      = R / QG; // 17 contiguous rows per thread
constexpr int   CHUNKS = N / T; // 64 chunks per batch

__device__ __forceinline__ float4 stencil(const float4 p, const float4 c,
                                          const float4 n) {
    float4 r;
    r.x = c.x + ALPHA * (p.x + n.x - 2.0f * c.x);
    r.y = c.y + ALPHA * (p.y + n.y - 2.0f * c.y);
    r.z = c.z + ALPHA * (p.z + n.z - 2.0f * c.z);
    r.w = c.w + ALPHA * (p.w + n.w - 2.0f * c.w);
    return r;
}

__global__ __launch_bounds__(QG * D4) void diffusion_halo(
        const float4* __restrict__ in4, float4* __restrict__ out4) {
    const int tid = threadIdx.x;
    const int d4  = tid & (D4 - 1);   // float4 lane along d
    const int q   = tid >> 5;         // row-group
    const int b   = blockIdx.x / CHUNKS;
    const int n0  = (blockIdx.x % CHUNKS) * T;

    __shared__ float4 lo[QG][D4];     // first row of each group (old values)
    __shared__ float4 hi[QG][D4];     // last  row of each group (old values)

    const int rbase = q * K;

    float4 s[K];
    // Load R rows with wraparound: global row ng = (n0 + r - HALO_L) mod N.
#pragma unroll
    for (int i = 0; i < K; ++i) {
        const int ng = (n0 + rbase + i + (N - HALO_L)) & (N - 1);
        s[i] = in4[(b * N + ng) * D4 + d4];
    }

    // out[0] = initial state (owned rows only)
#pragma unroll
    for (int i = 0; i < K; ++i) {
        const int r = rbase + i;
        if (r >= HALO_L && r < HALO_L + T) {
            out4[(b * N + (n0 + r - HALO_L)) * D4 + d4] = s[i];
        }
    }

    for (int k = 1; k <= STEPS; ++k) {
        // Publish old boundary rows of this group.
        lo[q][d4] = s[0];
        hi[q][d4] = s[K - 1];
        __syncthreads();
        const float4 bl = (q > 0)      ? hi[q - 1][d4]
                                       : make_float4(0.f, 0.f, 0.f, 0.f);
        const float4 bh = (q < QG - 1) ? lo[q + 1][d4]
                                       : make_float4(0.f, 0.f, 0.f, 0.f);
        __syncthreads();  // all reads done before next iteration's writes

        // In-register carry-chain stencil over this thread's K rows.
        float4 prev = bl;
#pragma unroll
        for (int i = 0; i < K; ++i) {
            const float4 cur = s[i];
            float4 nxt = bh;
            if (i + 1 < K) nxt = s[i + 1];
            s[i] = stencil(prev, cur, nxt);
            prev = cur;
        }

        // Store owned rows of out[k] — contiguous float4, fully coalesced.
        const int outbase = (k * B + b) * N;
#pragma unroll
        for (int i = 0; i < K; ++i) {
            const int r = rbase + i;
            if (r >= HALO_L && r < HALO_L + T) {
                out4[(outbase + (n0 + r - HALO_L)) * D4 + d4] = s[i];
            }
        }
    }
}

}  // namespace

extern "C" void kernel_launch(void* const* d_in, const int* in_sizes, int n_in,
                              void* d_out, int out_size, void* d_ws, size_t ws_size,
                              hipStream_t stream) {
    const float4* in4  = reinterpret_cast<const float4*>(d_in[0]);
    float4*       out4 = reinterpret_cast<float4*>(d_out);

    dim3 grid(B * CHUNKS);   // 512 blocks -> 2 per CU
    dim3 block(QG * D4);     // 256 threads
    diffusion_halo<<<grid, block, 0, stream>>>(in4, out4);
}

// Round 2
// 90.623 us; speedup vs baseline: 1.0088x; 1.0088x over previous
//
#include <hip/hip_runtime.h>

// 1D periodic diffusion, 50 steps, emit all intermediate states.
// out[t,b,n,d], t=0..50. Write-BW-bound (428 MB out). Halo/trapezoid
// decomposition: each block owns T rows of n for one b, loads T+104 rows
// (>=50 halo each side, wraparound at load), runs all 50 steps in
// registers, stores each step's owned rows. No inter-block sync.
//
// R2 change: __syncthreads() forces s_waitcnt vmcnt(0) each step (drains all
// global stores -> ~1100 cyc/step serial stall). Replace with raw s_barrier +
// explicit lgkmcnt(0) (LDS ordering only); double-buffer the lo/hi LDS board
// so only ONE barrier per step is needed. Stores stay in flight across
// barriers; vmcnt saturation throttles at memory speed (the roofline).

namespace {

constexpr int   B      = 8;
constexpr int   N      = 2048;
constexpr int   D4     = 32;    // 128 floats = 32 float4 per row
constexpr int   STEPS  = 50;
constexpr float ALPHA  = 0.1f;
constexpr int   T      = 32;    // owned rows per block
constexpr int   HALO_L = 50;
constexpr int   R      = 136;   // T + 104 >= T + 100, multiple of QG
constexpr int   QG     = 8;     // row-groups (q) per block
constexpr int   K      = R / QG; // 17 contiguous rows per thread
constexpr int   CHUNKS = N / T; // 64 chunks per batch

__device__ __forceinline__ float4 stencil(const float4 p, const float4 c,
                                          const float4 n) {
    float4 r;
    r.x = c.x + ALPHA * (p.x + n.x - 2.0f * c.x);
    r.y = c.y + ALPHA * (p.y + n.y - 2.0f * c.y);
    r.z = c.z + ALPHA * (p.z + n.z - 2.0f * c.z);
    r.w = c.w + ALPHA * (p.w + n.w - 2.0f * c.w);
    return r;
}

__global__ __launch_bounds__(QG * D4) void diffusion_halo(
        const float4* __restrict__ in4, float4* __restrict__ out4) {
    const int tid = threadIdx.x;
    const int d4  = tid & (D4 - 1);   // float4 lane along d
    const int q   = tid >> 5;         // row-group
    const int b   = blockIdx.x / CHUNKS;
    const int n0  = (blockIdx.x % CHUNKS) * T;

    // Double-buffered boundary board: one barrier per step.
    __shared__ float4 lo[2][QG][D4];  // first row of each group (old values)
    __shared__ float4 hi[2][QG][D4];  // last  row of each group (old values)

    const int rbase = q * K;

    float4 s[K];
    // Load R rows with wraparound: global row ng = (n0 + r - HALO_L) mod N.
#pragma unroll
    for (int i = 0; i < K; ++i) {
        const int ng = (n0 + rbase + i + (N - HALO_L)) & (N - 1);
        s[i] = in4[(b * N + ng) * D4 + d4];
    }

    // out[0] = initial state (owned rows only)
#pragma unroll
    for (int i = 0; i < K; ++i) {
        const int r = rbase + i;
        if (r >= HALO_L && r < HALO_L + T) {
            out4[(b * N + (n0 + r - HALO_L)) * D4 + d4] = s[i];
        }
    }

    for (int k = 1; k <= STEPS; ++k) {
        const int buf = k & 1;
        // Publish old boundary rows of this group.
        lo[buf][q][d4] = s[0];
        hi[buf][q][d4] = s[K - 1];
        // LDS ordering only — do NOT drain vmcnt (global stores stay in
        // flight across the barrier; no other block reads them).
        asm volatile("s_waitcnt lgkmcnt(0)" ::: "memory");
        __builtin_amdgcn_s_barrier();
        const float4 bl = (q > 0)      ? hi[buf][q - 1][d4]
                                       : make_float4(0.f, 0.f, 0.f, 0.f);
        const float4 bh = (q < QG - 1) ? lo[buf][q + 1][d4]
                                       : make_float4(0.f, 0.f, 0.f, 0.f);
        // No second barrier: next iteration writes buf^1, which cannot
        // conflict with this iteration's reads of buf; reuse of buf (two
        // steps later) is fenced by the intervening lgkmcnt(0)+barrier.

        // In-register carry-chain stencil; store owned rows as soon as
        // they are produced (earlier store issue).
        const int outbase = (k * B + b) * N;
        float4 prev = bl;
#pragma unroll
        for (int i = 0; i < K; ++i) {
            const float4 cur = s[i];
            float4 nxt = bh;
            if (i + 1 < K) nxt = s[i + 1];
            s[i] = stencil(prev, cur, nxt);
            prev = cur;
            const int r = rbase + i;
            if (r >= HALO_L && r < HALO_L + T) {
                out4[(outbase + (n0 + r - HALO_L)) * D4 + d4] = s[i];
            }
        }
    }
}

}  // namespace

extern "C" void kernel_launch(void* const* d_in, const int* in_sizes, int n_in,
                              void* d_out, int out_size, void* d_ws, size_t ws_size,
                              hipStream_t stream) {
    const float4* in4  = reinterpret_cast<const float4*>(d_in[0]);
    float4*       out4 = reinterpret_cast<float4*>(d_out);

    dim3 grid(B * CHUNKS);   // 512 blocks -> 2 per CU
    dim3 block(QG * D4);     // 256 threads
    diffusion_halo<<<grid, block, 0, stream>>>(in4, out4);
}

// Round 4
// 89.927 us; speedup vs baseline: 1.0166x; 1.0077x over previous
//
#include <hip/hip_runtime.h>

// 1D periodic diffusion, 50 steps, emit all intermediate states.
// out[t,b,n,d], t=0..50. Write-BW-bound (428 MB out). Halo/trapezoid
// decomposition: each block owns T=32 rows of n for one (b, d-half), loads
// R=144 rows (56-row halo each side, wraparound at load), runs all 50 steps
// in registers, stores each step's owned rows. No inter-block comms.
//
// R3 change (post-mortem R2: barrier drain was NOT the stall; 2 blocks/CU
// lockstep left issue bubbles): split d across 2 blocks -> 1024 blocks
// (4/CU, 4 waves/SIMD), K drops 17->9 (fewer VGPRs), 2x store-issuing
// waves/CU, staggered phases smooth write bursts. Output stores are
// nontemporal (never re-read; don't thrash 32MB L2 with a 428MB stream).
// R4: use clang ext_vector float4 (HIP_vector_type rejected by
// __builtin_nontemporal_store).

namespace {

typedef float f4 __attribute__((ext_vector_type(4)));

constexpr int   B      = 8;
constexpr int   N      = 2048;
constexpr int   D4     = 32;    // 128 floats = 32 float4 per row (global)
constexpr int   SPLITD = 2;     // d-halves per row
constexpr int   D4L    = D4 / SPLITD;  // 16 float4 lanes per block
constexpr int   STEPS  = 50;
constexpr float ALPHA  = 0.1f;
constexpr int   T      = 32;    // owned rows per block
constexpr int   QG     = 16;    // row-groups per block (256 thr / 16 lanes)
constexpr int   K      = 9;     // rows per thread
constexpr int   R      = QG * K;        // 144 staged rows
constexpr int   HALO_L = (R - T) / 2;   // 56 >= 50 needed
constexpr int   CHUNKS = N / T; // 64 chunks per batch

__device__ __forceinline__ f4 stencil(const f4 p, const f4 c, const f4 n) {
    return c + ALPHA * (p + n - 2.0f * c);
}

__global__ __launch_bounds__(QG * D4L, 4) void diffusion_halo(
        const f4* __restrict__ in4, f4* __restrict__ out4) {
    const int tid = threadIdx.x;
    const int d4l = tid & (D4L - 1);  // float4 lane within this d-half
    const int q   = tid >> 4;         // row-group 0..15

    const int bid = blockIdx.x;
    const int dh  = bid & (SPLITD - 1);            // d-half
    const int c   = (bid >> 1) & (CHUNKS - 1);     // n-chunk
    const int b   = bid >> 7;                      // batch (1024/128)
    const int n0  = c * T;
    const int d4g = dh * D4L + d4l;                // global float4 column

    // Double-buffered boundary board: one barrier per step.
    __shared__ f4 lo[2][QG][D4L];
    __shared__ f4 hi[2][QG][D4L];

    const int rbase = q * K;

    f4 s[K];
    // Load R rows with wraparound: global row ng = (n0 + r - HALO_L) mod N.
#pragma unroll
    for (int i = 0; i < K; ++i) {
        const int ng = (n0 + rbase + i + (N - HALO_L)) & (N - 1);
        s[i] = in4[(b * N + ng) * D4 + d4g];
    }

    // out[0] = initial state (owned rows only)
#pragma unroll
    for (int i = 0; i < K; ++i) {
        const int r = rbase + i;
        if (r >= HALO_L && r < HALO_L + T) {
            __builtin_nontemporal_store(
                s[i], &out4[(b * N + (n0 + r - HALO_L)) * D4 + d4g]);
        }
    }

    for (int k = 1; k <= STEPS; ++k) {
        const int buf = k & 1;
        // Publish old boundary rows of this group.
        lo[buf][q][d4l] = s[0];
        hi[buf][q][d4l] = s[K - 1];
        // LDS ordering only — do NOT drain vmcnt (stores stay in flight).
        asm volatile("s_waitcnt lgkmcnt(0)" ::: "memory");
        __builtin_amdgcn_s_barrier();
        const f4 bl = (q > 0)      ? hi[buf][q - 1][d4l] : (f4)(0.f);
        const f4 bh = (q < QG - 1) ? lo[buf][q + 1][d4l] : (f4)(0.f);
        // No second barrier: next iter writes buf^1; reuse of buf two steps
        // later is fenced by the intervening lgkmcnt(0)+barrier (reads of
        // buf complete before this wave's next lgkmcnt(0) drain).

        // In-register carry-chain stencil; store owned rows as produced.
        const int outbase = (k * B + b) * N;
        f4 prev = bl;
#pragma unroll
        for (int i = 0; i < K; ++i) {
            const f4 cur = s[i];
            f4 nxt = bh;
            if (i + 1 < K) nxt = s[i + 1];
            s[i] = stencil(prev, cur, nxt);
            prev = cur;
            const int r = rbase + i;
            if (r >= HALO_L && r < HALO_L + T) {
                __builtin_nontemporal_store(
                    s[i], &out4[(outbase + (n0 + r - HALO_L)) * D4 + d4g]);
            }
        }
    }
}

}  // namespace

extern "C" void kernel_launch(void* const* d_in, const int* in_sizes, int n_in,
                              void* d_out, int out_size, void* d_ws, size_t ws_size,
                              hipStream_t stream) {
    const f4* in4  = reinterpret_cast<const f4*>(d_in[0]);
    f4*       out4 = reinterpret_cast<f4*>(d_out);

    dim3 grid(B * CHUNKS * SPLITD);  // 1024 blocks -> 4 per CU
    dim3 block(QG * D4L);            // 256 threads
    diffusion_halo<<<grid, block, 0, stream>>>(in4, out4);
}